// Round 17
// baseline (57.664 us; speedup 1.0000x reference)
//
#include <hip/hip_runtime.h>
#include <hip/hip_bf16.h>
#include <stdint.h>

// SimCLR loss, n=8192, d=128, T=0.07.
// R17 = R13 skeleton (4 dispatches; fragment-major layout; no LDS/barriers/
// atomics in k_simexp; grid 1024, 64 rows/wave, 1 slice/block — the proven
// balance point) with the MFMA data path switched to FP8 e4m3:
//  - mfma_f32_16x16x32_fp8_fp8 has the SAME fragment geometry as bf16
//    16x16x32 (8 elems/lane, same row/k map, same C/D layout) -> A/B load
//    bytes HALVE (L1-return pipe 8.5 -> 4.3us) and Af VGPRs halve (64->32,
//    occupancy headroom).
//  - fn stores bf16(dequant(fp8)) — e4m3 fits exactly in bf16 — so
//    finalize's self-dot exactly matches the MFMA diagonal (cancellation
//    preserved; this is critical since E-minus-diag ~ 0.01).
// R16 lesson: grid must stay >= 1024 (2 blocks/CU = TLP collapse).
//  k_normalize: fp32 -> fn (bf16-of-fp8, row-major) + fnB (fp8 frag-major)
//  k_simexp:    E_part[row][slice] = sum_j exp2((dot-1)*s)  (plain stores)
//  k_finalize:  per-row term -> terms[];  k_reduce: mean -> out[0]

#define N_ROWS 8192
#define DIM    128
#define HALF_N 4096
#define N_SLICES 32
#define NT 16                     // 16-col tiles per 256-col slice
#define ROWS_PER_BLOCK 256        // 4 waves x 64 rows

static constexpr float INV_T = 14.285714285714286f;   // 1/0.07
static constexpr float SCALE = 20.60992915555662f;    // log2(e)/0.07

typedef __attribute__((ext_vector_type(4))) float f32x4;

#if __has_builtin(__builtin_amdgcn_exp2f)
__device__ inline float fast_exp2(float x) { return __builtin_amdgcn_exp2f(x); }
#else
__device__ inline float fast_exp2(float x) { return exp2f(x); }
#endif

__device__ inline float bf_lo(uint32_t u) { return __uint_as_float(u << 16); }
__device__ inline float bf_hi(uint32_t u) { return __uint_as_float(u & 0xFFFF0000u); }
__device__ inline uint16_t f2bf(float x) {
    uint32_t u = __float_as_uint(x);
    return (uint16_t)((u + 0x7FFFu + ((u >> 16) & 1u)) >> 16);   // RNE
}

// fnB (fp8) layout, 8-byte chunks: chunk(row j, dim k) =
//   (j>>4)*256 + (k>>5)*64 + ((k>>3)&3)*16 + (j&15); byte-in-chunk = k&7.
// Fragment load for lane l: fnB64[tile*256 + kc*64 + l] holds row
// tile*16+(l&15), dims kc*32+(l>>4)*8..+8 — identical mapping to the bf16
// version, at half the bytes. A and B fragments are identical gathers.

// ---------------- kernel 1: normalize -> fn (bf16-of-fp8) + fnB (fp8) -----
__global__ __launch_bounds__(256) void k_normalize(const float* __restrict__ f,
                                                   uint16_t* __restrict__ fn,
                                                   uint8_t* __restrict__ fnB) {
    int wid  = (blockIdx.x * blockDim.x + threadIdx.x) >> 6;   // one wave per row
    int lane = threadIdx.x & 63;
    const float2* src = (const float2*)(f + (size_t)wid * DIM);
    float2 v = src[lane];
    float ss = v.x * v.x + v.y * v.y;
    #pragma unroll
    for (int m = 1; m < 64; m <<= 1) ss += __shfl_xor(ss, m, 64);
    float inv = rsqrtf(ss);

    // quantize the normalized pair to fp8 e4m3 (hardware cvt), bytes 0,1
    int pk = __builtin_amdgcn_cvt_pk_fp8_f32(v.x * inv, v.y * inv, 0, false);
    // dequantized values (exact in bf16) for the finalize pass
    float d0 = __builtin_amdgcn_cvt_f32_fp8(pk, 0);
    float d1 = __builtin_amdgcn_cvt_f32_fp8(pk, 1);
    ushort2 o;
    o.x = f2bf(d0);
    o.y = f2bf(d1);
    ((ushort2*)(fn + (size_t)wid * DIM))[lane] = o;              // row-major

    int k0 = lane * 2;                                            // frag-major
    size_t chunk = (size_t)(wid >> 4) * 256 + (k0 >> 5) * 64 +
                   ((k0 >> 3) & 3) * 16 + (wid & 15);
    *(uint16_t*)(fnB + chunk * 8 + (k0 & 7)) = (uint16_t)(pk & 0xFFFF);
}

// ---------------- kernel 2: sim + exp-sum (fp8 MFMA, frag-major) ----------
// Grid (32, 32): block = 4 waves x 64 rows = 256 rows, 256 cols (16 tiles).
__global__ __launch_bounds__(256) void k_simexp(const uint8_t* __restrict__ fnB,
                                                float* __restrict__ E_part) {
    const int lane  = threadIdx.x & 63;
    const int w     = threadIdx.x >> 6;
    const int ib    = blockIdx.x * ROWS_PER_BLOCK + w * 64;
    const int slice = blockIdx.y;
    const int lr = lane & 15;
    const int lk = lane >> 4;

    const long* fnB64 = (const long*)fnB;      // 8B fragment chunks
    const int tileA0 = ib >> 4;
    const int jt0    = slice * NT;             // first B tile of this slice

    // A fragments: one coalesced 512B load each (16 total, 32 VGPRs)
    long Af[4][4];
    #pragma unroll
    for (int mt = 0; mt < 4; ++mt)
        #pragma unroll
        for (int kc = 0; kc < 4; ++kc)
            Af[mt][kc] = fnB64[(size_t)(tileA0 + mt) * 256 + kc * 64 + lane];

    float es[4][4];
    #pragma unroll
    for (int mt = 0; mt < 4; ++mt)
        #pragma unroll
        for (int r = 0; r < 4; ++r) es[mt][r] = 0.0f;

    const long* bbase = fnB64 + (size_t)jt0 * 256 + lane;

    for (int jt = 0; jt < NT; ++jt) {
        const long* bp = bbase + (size_t)jt * 256;
        long Bf[4];
        #pragma unroll
        for (int kc = 0; kc < 4; ++kc)
            Bf[kc] = bp[kc * 64];              // coalesced 512B per load
        #pragma unroll
        for (int mt = 0; mt < 4; ++mt) {
            f32x4 acc = {0.0f, 0.0f, 0.0f, 0.0f};
            #pragma unroll
            for (int kc = 0; kc < 4; ++kc)
                acc = __builtin_amdgcn_mfma_f32_16x16x32_fp8_fp8(Af[mt][kc], Bf[kc], acc, 0, 0, 0);
            #pragma unroll
            for (int r = 0; r < 4; ++r)
                es[mt][r] += fast_exp2(fmaf(acc[r], SCALE, -SCALE));
        }
    }

    // C/D (shape-determined, dtype-independent): col = lane&15, row = lk*4+r.
    #pragma unroll
    for (int mt = 0; mt < 4; ++mt)
        #pragma unroll
        for (int r = 0; r < 4; ++r) {
            float v = es[mt][r];
            v += __shfl_xor(v, 1, 64);
            v += __shfl_xor(v, 2, 64);
            v += __shfl_xor(v, 4, 64);
            v += __shfl_xor(v, 8, 64);
            if (lr == 0)
                E_part[(size_t)(ib + mt * 16 + lk * 4 + r) * N_SLICES + slice] = v;
        }
}

// ---------------- kernel 3: per-row finalize -> block partials ------------
__global__ __launch_bounds__(256) void k_finalize(const uint16_t* __restrict__ fn,
                                                  const float* __restrict__ E_part,
                                                  float* __restrict__ terms) {
    __shared__ float sm[4];
    int wid  = (blockIdx.x * blockDim.x + threadIdx.x) >> 6;   // one wave per row
    int lane = threadIdx.x & 63;
    int partner = (wid + HALF_N) & (N_ROWS - 1);
    const uint32_t* fr = (const uint32_t*)(fn + (size_t)wid * DIM);
    const uint32_t* pr = (const uint32_t*)(fn + (size_t)partner * DIM);
    uint32_t a = fr[lane], p = pr[lane];
    float a0 = bf_lo(a), a1 = bf_hi(a);
    float p0 = bf_lo(p), p1 = bf_hi(p);
    float sd = a0 * a0 + a1 * a1;       // self dot of fp8-quantized row
    float pd = a0 * p0 + a1 * p1;       // positive-pair dot (same values)
    #pragma unroll
    for (int m = 1; m < 64; m <<= 1) {
        sd += __shfl_xor(sd, m, 64);
        pd += __shfl_xor(pd, m, 64);
    }
    float e = (lane < N_SLICES) ? E_part[(size_t)wid * N_SLICES + lane] : 0.0f;
    #pragma unroll
    for (int m = 1; m < 64; m <<= 1) e += __shfl_xor(e, m, 64);
    if (lane == 0) {
        float ep = e - fast_exp2(fmaf(sd, SCALE, -SCALE));   // remove diagonal
        sm[threadIdx.x >> 6] = INV_T + logf(ep) - pd * INV_T;
    }
    __syncthreads();
    if (threadIdx.x == 0)
        terms[blockIdx.x] = sm[0] + sm[1] + sm[2] + sm[3];
}

// ---------------- kernel 4: mean over 2048 block partials ----------------
__global__ __launch_bounds__(256) void k_reduce(const float* __restrict__ terms,
                                                float* __restrict__ out) {
    __shared__ float sm[4];
    float acc = 0.0f;
    for (int i = threadIdx.x; i < N_ROWS / 4; i += 256) acc += terms[i];
    #pragma unroll
    for (int m = 1; m < 64; m <<= 1) acc += __shfl_xor(acc, m, 64);
    if ((threadIdx.x & 63) == 0) sm[threadIdx.x >> 6] = acc;
    __syncthreads();
    if (threadIdx.x == 0)
        out[0] = (sm[0] + sm[1] + sm[2] + sm[3]) * (1.0f / N_ROWS);
}

extern "C" void kernel_launch(void* const* d_in, const int* in_sizes, int n_in,
                              void* d_out, int out_size, void* d_ws, size_t ws_size,
                              hipStream_t stream) {
    const float* feat = (const float*)d_in[0];
    float* out = (float*)d_out;

    // ws: fn (2 MiB) | fnB fp8 (1 MiB) | E_part (1 MiB) | terms (8 KiB)
    uint16_t* fn  = (uint16_t*)d_ws;
    uint8_t*  fnB = (uint8_t*)(fn + (size_t)N_ROWS * DIM);
    float* E_part = (float*)(fnB + (size_t)N_ROWS * DIM);
    float* terms  = E_part + (size_t)N_ROWS * N_SLICES;

    k_normalize<<<dim3(N_ROWS / 4), dim3(256), 0, stream>>>(feat, fn, fnB);
    k_simexp<<<dim3(N_ROWS / ROWS_PER_BLOCK, N_SLICES), dim3(256), 0, stream>>>(fnB, E_part);
    k_finalize<<<dim3(N_ROWS / 4), dim3(256), 0, stream>>>(fn, E_part, terms);
    k_reduce<<<dim3(1), dim3(256), 0, stream>>>(terms, out);
}